// Round 4
// baseline (418.983 us; speedup 1.0000x reference)
//
#include <hip/hip_runtime.h>
#include <hip/hip_bf16.h>

// ---------------- static problem constants ----------------
static constexpr int BS     = 4;
static constexpr int EMBED  = 256;
static constexpr int HEADS  = 8;
static constexpr int LEVELS = 4;
static constexpr int POINTS = 4;
static constexpr int HD     = 32;               // EMBED / HEADS
static constexpr int LQ     = 12240;            // sum of level areas
static constexpr int NROW   = BS * LQ;          // 48960 rows
static constexpr int LVL_W[4]  = {96, 48, 24, 12};
static constexpr int LVL_H[4]  = {96, 48, 24, 12};
static constexpr int LVL_ST[4] = {0, 9216, 11520, 12096};

typedef __attribute__((ext_vector_type(8))) short short8;            // bf16x8 MFMA frag
typedef __attribute__((ext_vector_type(4))) float f32x4;
typedef __attribute__((ext_vector_type(8))) unsigned short ushort8v;

__device__ __forceinline__ unsigned short f2bf(float f) {
    unsigned int u = __float_as_uint(f);
    unsigned int r = (u + 0x7FFFu + ((u >> 16) & 1u)) >> 16;   // RNE
    return (unsigned short)r;
}
__device__ __forceinline__ float bf2f(unsigned short b) {
    return __uint_as_float(((unsigned int)b) << 16);
}

// ---------------- weight prep: transpose + f32->bf16 ----------------
__global__ __launch_bounds__(256) void prep_weights(
    const float* __restrict__ W_off, const float* __restrict__ W_attn,
    const float* __restrict__ W_val, const float* __restrict__ W_out,
    unsigned short* __restrict__ WT_oa, unsigned short* __restrict__ WT_val,
    unsigned short* __restrict__ WT_out)
{
    const int gid = blockIdx.x * 256 + threadIdx.x;   // 896*256 total
    const int k = gid & 255;
    const int n = gid >> 8;
    if (n < 384) {
        const float v = (n < 256) ? W_off[k * 256 + n] : W_attn[k * 128 + (n - 256)];
        WT_oa[n * 256 + k] = f2bf(v);
    } else if (n < 640) {
        const int nn = n - 384;
        WT_val[nn * 256 + k] = f2bf(W_val[k * 256 + nn]);
    } else {
        const int nn = n - 640;
        WT_out[nn * 256 + k] = f2bf(W_out[k * 256 + nn]);
    }
}

// ---------------- bf16 MFMA GEMM: C[M,N] = A[M,256] @ Wt^T + bias ----------------
// Block = 64 rows x NB=NTW*64 cols, 256 threads = 4 waves, waves split by column.
// Wave w owns col-frags [w*NTW,(w+1)*NTW), each 16 cols, over 4 row-groups of 16.
// A-frag: A[m=lane&15][k=(lane>>4)*8+j]; B-frag: B[k][n=lane&15]; D: col=lane&15,
// row=(lane>>4)*4+reg (HW-verified).
// FUSE_LOC (GEMM2 only, N=384, gridDim.x=1): epilogue applies softmax to attn
// cols (256..383, one frag per (row,head)) and the ref-point/pixel transform to
// offset cols (0..255), writing final LOC/AW straight to OA.
template <int NTW, bool A_BF16, bool OUT_BF16, bool FUSE_LOC>
__global__ __launch_bounds__(256) void gemm_mfma(
    const void* __restrict__ Av, const unsigned short* __restrict__ Wt,
    const float* __restrict__ bias0, const float* __restrict__ bias1, int nsplit,
    void* __restrict__ Cv, int N, const float* __restrict__ refp)
{
    constexpr int NB = NTW * 64;
    constexpr int K  = 256;
    __shared__ __align__(16) unsigned short As[64][40];   // [m][k]
    __shared__ __align__(16) unsigned short Bs[NB][40];   // [n][k]
    __shared__ float refs[FUSE_LOC ? 64 * 8 : 1];         // refp rows of this block

    const int tid = threadIdx.x;
    const int m0 = blockIdx.y * 64;
    const int n0 = blockIdx.x * NB;
    const int w  = tid >> 6;
    const int l  = tid & 63;
    const int lm = l & 15;
    const int lq = l >> 4;

    const int sr = tid >> 2;          // staging row 0..63
    const int kg = (tid & 3) * 8;     // staging k offset 0,8,16,24

    if (FUSE_LOC && tid < 128) {      // stage refp for 64 rows (8 f32 each)
        *(float4*)&refs[tid * 4] = *(const float4*)&refp[(size_t)m0 * 8 + tid * 4];
    }

    f32x4 acc[4][NTW];
    #pragma unroll
    for (int rg = 0; rg < 4; ++rg)
        #pragma unroll
        for (int nt = 0; nt < NTW; ++nt)
            acc[rg][nt] = (f32x4){0.f, 0.f, 0.f, 0.f};

    for (int k0 = 0; k0 < K; k0 += 32) {
        // ---- stage A tile (64 x 32) ----
        if (A_BF16) {
            const unsigned short* A = (const unsigned short*)Av;
            *(short8*)&As[sr][kg] = *(const short8*)&A[(size_t)(m0 + sr) * K + k0 + kg];
        } else {
            const float* A = (const float*)Av;
            const float* ap = &A[(size_t)(m0 + sr) * K + k0 + kg];
            const float4 x = *(const float4*)ap;
            const float4 y = *(const float4*)(ap + 4);
            uint4 pk;
            pk.x = (unsigned int)f2bf(x.x) | ((unsigned int)f2bf(x.y) << 16);
            pk.y = (unsigned int)f2bf(x.z) | ((unsigned int)f2bf(x.w) << 16);
            pk.z = (unsigned int)f2bf(y.x) | ((unsigned int)f2bf(y.y) << 16);
            pk.w = (unsigned int)f2bf(y.z) | ((unsigned int)f2bf(y.w) << 16);
            *(uint4*)&As[sr][kg] = pk;
        }
        // ---- stage B tile (NB x 32) from Wt[N][K] ----
        #pragma unroll
        for (int i = 0; i < NTW; ++i) {
            const int slot = tid + i * 256;
            const int n  = slot >> 2;
            const int kk = (slot & 3) * 8;
            *(short8*)&Bs[n][kk] = *(const short8*)&Wt[(size_t)(n0 + n) * K + k0 + kk];
        }
        __syncthreads();

        short8 af[4];
        #pragma unroll
        for (int rg = 0; rg < 4; ++rg)
            af[rg] = *(const short8*)&As[rg * 16 + lm][lq * 8];
        #pragma unroll
        for (int nt = 0; nt < NTW; ++nt) {
            const short8 bf = *(const short8*)&Bs[(w * NTW + nt) * 16 + lm][lq * 8];
            #pragma unroll
            for (int rg = 0; rg < 4; ++rg)
                acc[rg][nt] = __builtin_amdgcn_mfma_f32_16x16x32_bf16(af[rg], bf, acc[rg][nt], 0, 0, 0);
        }
        __syncthreads();
    }

    // ---- epilogue ----
    #pragma unroll
    for (int nt = 0; nt < NTW; ++nt) {
        const int colbase = n0 + (w * NTW + nt) * 16;
        const int col = colbase + lm;
        if (!FUSE_LOC) {
            const float b = (col < nsplit) ? bias0[col] : bias1[col - nsplit];
            #pragma unroll
            for (int rg = 0; rg < 4; ++rg)
                #pragma unroll
                for (int r = 0; r < 4; ++r) {
                    const int row = m0 + rg * 16 + lq * 4 + r;
                    const float v = acc[rg][nt][r] + b;
                    if (OUT_BF16) ((unsigned short*)Cv)[(size_t)row * N + col] = f2bf(v);
                    else          ((float*)Cv)[(size_t)row * N + col] = v;
                }
        } else if (colbase >= 256) {
            // ---- attention softmax: cols 256+h*16 .. +16 == one frag ----
            const float b = bias1[col - 256];
            #pragma unroll
            for (int rg = 0; rg < 4; ++rg)
                #pragma unroll
                for (int r = 0; r < 4; ++r) {
                    float v = acc[rg][nt][r] + b;
                    float m = v;
                    #pragma unroll
                    for (int d = 8; d >= 1; d >>= 1) m = fmaxf(m, __shfl_xor(m, d, 16));
                    const float e = __expf(v - m);
                    float s = e;
                    #pragma unroll
                    for (int d = 8; d >= 1; d >>= 1) s += __shfl_xor(s, d, 16);
                    const int row = m0 + rg * 16 + lq * 4 + r;
                    ((float*)Cv)[(size_t)row * N + col] = e / s;
                }
        } else {
            // ---- offset -> pixel coords ----
            const float b = bias0[col];
            const int pi  = col >> 1;           // h*16 + lp
            const int lvl = (pi >> 2) & 3;
            const int isY = col & 1;
            const float S = (float)(isY ? LVL_H[lvl] : LVL_W[lvl]);
            #pragma unroll
            for (int rg = 0; rg < 4; ++rg)
                #pragma unroll
                for (int r = 0; r < 4; ++r) {
                    const int rl = rg * 16 + lq * 4 + r;
                    const float rp = refs[rl * 8 + lvl * 2 + isY];
                    const float v = acc[rg][nt][r] + b;
                    const float loc = rp + v / S;      // mimic reference op order
                    ((float*)Cv)[(size_t)(m0 + rl) * N + col] = loc * S - 0.5f;
                }
        }
    }
}

// ---------------- bilinear sampling + weighted accumulation (bf16 V) ----------------
// 32 threads per row: t -> h = t/4, c8 = (t%4)*8 (8 channels, ushort8 = 16B loads).
// Block = 256 threads = 8 consecutive rows (no swizzle — natural batch-major order).
__global__ __launch_bounds__(256) void sample_kernel(
    const unsigned short* __restrict__ V,   // bf16 [b, pix, 256]
    const float* __restrict__ OA,           // [row][384]: coords then weights
    unsigned short* __restrict__ ACC)       // bf16 [row][256]
{
    const int tid = threadIdx.x;
    const int row = blockIdx.x * 8 + (tid >> 5);
    const int b   = blockIdx.x / (LQ / 8);  // 1530 blocks per batch
    const int t  = tid & 31;
    const int h  = t >> 2;
    const int c8 = (t & 3) * 8;

    const float* locr = OA + (size_t)row * 384 + h * 32;        // 16 (gx,gy)
    const float* awr  = OA + (size_t)row * 384 + 256 + h * 16;  // 16 weights
    const unsigned short* vb = V + ((size_t)b * LQ * EMBED + h * HD + c8);

    float a[8];
    #pragma unroll
    for (int j = 0; j < 8; ++j) a[j] = 0.f;

    #pragma unroll
    for (int l = 0; l < 4; ++l) {
        const int Wl = LVL_W[l], Hl = LVL_H[l], st = LVL_ST[l];
        #pragma unroll
        for (int p = 0; p < 4; ++p) {
            const int lp = l * 4 + p;
            const float gx = locr[lp * 2 + 0];
            const float gy = locr[lp * 2 + 1];
            const float wgt = awr[lp];

            const float fx = floorf(gx), fy = floorf(gy);
            const float wx = gx - fx,    wy = gy - fy;
            const int x0 = (int)fx, y0 = (int)fy;
            const int x1 = x0 + 1,  y1 = y0 + 1;

            const bool bx0 = ((unsigned)x0 < (unsigned)Wl);
            const bool bx1 = ((unsigned)x1 < (unsigned)Wl);
            const bool by0 = ((unsigned)y0 < (unsigned)Hl);
            const bool by1 = ((unsigned)y1 < (unsigned)Hl);
            const float w00 = (bx0 && by0) ? (1.f - wx) * (1.f - wy) * wgt : 0.f;
            const float w01 = (bx1 && by0) ? wx * (1.f - wy) * wgt : 0.f;
            const float w10 = (bx0 && by1) ? (1.f - wx) * wy * wgt : 0.f;
            const float w11 = (bx1 && by1) ? wx * wy * wgt : 0.f;

            const int cx0 = min(max(x0, 0), Wl - 1);
            const int cx1 = min(max(x1, 0), Wl - 1);
            const int cy0 = min(max(y0, 0), Hl - 1);
            const int cy1 = min(max(y1, 0), Hl - 1);
            const int i00 = (st + cy0 * Wl + cx0) * EMBED;
            const int i01 = (st + cy0 * Wl + cx1) * EMBED;
            const int i10 = (st + cy1 * Wl + cx0) * EMBED;
            const int i11 = (st + cy1 * Wl + cx1) * EMBED;

            const ushort8v u00 = *(const ushort8v*)(vb + i00);
            const ushort8v u01 = *(const ushort8v*)(vb + i01);
            const ushort8v u10 = *(const ushort8v*)(vb + i10);
            const ushort8v u11 = *(const ushort8v*)(vb + i11);

            #pragma unroll
            for (int j = 0; j < 8; ++j) {
                float aj = a[j];
                aj = fmaf(w00, bf2f(u00[j]), aj);
                aj = fmaf(w01, bf2f(u01[j]), aj);
                aj = fmaf(w10, bf2f(u10[j]), aj);
                aj = fmaf(w11, bf2f(u11[j]), aj);
                a[j] = aj;
            }
        }
    }
    ushort8v o;
    #pragma unroll
    for (int j = 0; j < 8; ++j) o[j] = f2bf(a[j]);
    *(ushort8v*)(ACC + (size_t)row * EMBED + h * HD + c8) = o;
}

// ---------------- launch ----------------
extern "C" void kernel_launch(void* const* d_in, const int* in_sizes, int n_in,
                              void* d_out, int out_size, void* d_ws, size_t ws_size,
                              hipStream_t stream) {
    const float* query  = (const float*)d_in[0];
    const float* refp   = (const float*)d_in[1];
    const float* value  = (const float*)d_in[2];
    // d_in[3] = value_spatial_shapes (static, hard-coded)
    const float* W_off  = (const float*)d_in[4];
    const float* b_off  = (const float*)d_in[5];
    const float* W_attn = (const float*)d_in[6];
    const float* b_attn = (const float*)d_in[7];
    const float* W_val  = (const float*)d_in[8];
    const float* b_val  = (const float*)d_in[9];
    const float* W_out  = (const float*)d_in[10];
    const float* b_out  = (const float*)d_in[11];
    float* out = (float*)d_out;

    // ---- workspace layout ----
    unsigned short* WT_oa  = (unsigned short*)d_ws;          // [384][256] bf16
    unsigned short* WT_val = WT_oa  + 384 * 256;             // [256][256] bf16
    unsigned short* WT_out = WT_val + 256 * 256;             // [256][256] bf16
    unsigned short* V      = WT_out + 256 * 256;             // [NROW][256] bf16
    float*          OA     = (float*)(V + (size_t)NROW * EMBED);        // [NROW][384] f32
    unsigned short* ACCb   = (unsigned short*)(OA + (size_t)NROW * 384); // [NROW][256] bf16

    dim3 blk(256);

    // 0. weight transpose + convert
    prep_weights<<<896, blk, 0, stream>>>(W_off, W_attn, W_val, W_out,
                                          WT_oa, WT_val, WT_out);
    // 1. V = bf16(value @ W_val + b_val)
    gemm_mfma<4, false, true, false><<<dim3(1, NROW / 64), blk, 0, stream>>>(
        value, WT_val, b_val, b_val, 256, V, 256, nullptr);
    // 2. OA = loc/softmax(query @ [W_off | W_attn] + bias)  — fused epilogue
    gemm_mfma<6, false, false, true><<<dim3(1, NROW / 64), blk, 0, stream>>>(
        query, WT_oa, b_off, b_attn, 256, OA, 384, refp);
    // 3. deformable sampling -> bf16 ACC
    sample_kernel<<<NROW / 8, blk, 0, stream>>>(V, OA, ACCb);
    // 4. out = ACC @ W_out + b_out
    gemm_mfma<4, true, false, false><<<dim3(1, NROW / 64), blk, 0, stream>>>(
        ACCb, WT_out, b_out, b_out, 256, out, 256, nullptr);
}

// Round 5
// 375.711 us; speedup vs baseline: 1.1152x; 1.1152x over previous
//
#include <hip/hip_runtime.h>
#include <hip/hip_bf16.h>

// ---------------- static problem constants ----------------
static constexpr int BS     = 4;
static constexpr int EMBED  = 256;
static constexpr int HEADS  = 8;
static constexpr int LEVELS = 4;
static constexpr int POINTS = 4;
static constexpr int HD     = 32;               // EMBED / HEADS
static constexpr int LQ     = 12240;            // sum of level areas
static constexpr int NROW   = BS * LQ;          // 48960 rows
static constexpr int LVL_W[4]  = {96, 48, 24, 12};
static constexpr int LVL_H[4]  = {96, 48, 24, 12};
static constexpr int LVL_ST[4] = {0, 9216, 11520, 12096};

typedef __attribute__((ext_vector_type(8))) short short8;            // bf16x8 MFMA frag
typedef __attribute__((ext_vector_type(4))) float f32x4;

__device__ __forceinline__ unsigned short f2bf(float f) {
    unsigned int u = __float_as_uint(f);
    unsigned int r = (u + 0x7FFFu + ((u >> 16) & 1u)) >> 16;   // RNE
    return (unsigned short)r;
}
__device__ __forceinline__ float bf2f(unsigned short b) {
    return __uint_as_float(((unsigned int)b) << 16);
}

// ---------------- weight prep: transpose + f32->bf16 ----------------
__global__ __launch_bounds__(256) void prep_weights(
    const float* __restrict__ W_off, const float* __restrict__ W_attn,
    const float* __restrict__ W_val, const float* __restrict__ W_out,
    unsigned short* __restrict__ WT_oa, unsigned short* __restrict__ WT_val,
    unsigned short* __restrict__ WT_out)
{
    const int gid = blockIdx.x * 256 + threadIdx.x;   // 896*256 total
    const int k = gid & 255;
    const int n = gid >> 8;
    if (n < 384) {
        const float v = (n < 256) ? W_off[k * 256 + n] : W_attn[k * 128 + (n - 256)];
        WT_oa[n * 256 + k] = f2bf(v);
    } else if (n < 640) {
        const int nn = n - 384;
        WT_val[nn * 256 + k] = f2bf(W_val[k * 256 + nn]);
    } else {
        const int nn = n - 640;
        WT_out[nn * 256 + k] = f2bf(W_out[k * 256 + nn]);
    }
}

// ---------------- bf16 MFMA GEMM with register-double-buffered staging ----------------
// C[M,N] = A[M,256] @ Wt^T + bias. Block = 64 rows x NB=NTW*64 cols, 4 waves split
// by column. Global loads for tile k+1 are issued right after the barrier, consumed
// at the next LDS store — hides HBM latency behind ds_read+MFMA.
template <int NTW, bool A_BF16, bool OUT_BF16>
__global__ __launch_bounds__(256) void gemm_mfma(
    const void* __restrict__ Av, const unsigned short* __restrict__ Wt,
    const float* __restrict__ bias0, const float* __restrict__ bias1, int nsplit,
    void* __restrict__ Cv, int N)
{
    constexpr int NB = NTW * 64;
    constexpr int K  = 256;
    __shared__ __align__(16) unsigned short As[64][40];
    __shared__ __align__(16) unsigned short Bs[NB][40];

    const int tid = threadIdx.x;
    const int m0 = blockIdx.y * 64;
    const int n0 = blockIdx.x * NB;
    const int w  = tid >> 6;
    const int l  = tid & 63;
    const int lm = l & 15;
    const int lq = l >> 4;

    const int sr = tid >> 2;          // staging row 0..63
    const int kg = (tid & 3) * 8;     // staging k offset 0,8,16,24

    float4 pa0, pa1; short8 pa_bf;    // A prefetch regs
    short8 pb[NTW];                   // B prefetch regs

    auto gload = [&](int k0) {
        if (A_BF16) {
            const unsigned short* A = (const unsigned short*)Av;
            pa_bf = *(const short8*)&A[(size_t)(m0 + sr) * K + k0 + kg];
        } else {
            const float* A = (const float*)Av;
            const float* ap = &A[(size_t)(m0 + sr) * K + k0 + kg];
            pa0 = *(const float4*)ap;
            pa1 = *(const float4*)(ap + 4);
        }
        #pragma unroll
        for (int i = 0; i < NTW; ++i) {
            const int slot = tid + i * 256;
            const int n  = slot >> 2;
            const int kk = (slot & 3) * 8;
            pb[i] = *(const short8*)&Wt[(size_t)(n0 + n) * K + k0 + kk];
        }
    };

    f32x4 acc[4][NTW];
    #pragma unroll
    for (int rg = 0; rg < 4; ++rg)
        #pragma unroll
        for (int nt = 0; nt < NTW; ++nt)
            acc[rg][nt] = (f32x4){0.f, 0.f, 0.f, 0.f};

    gload(0);
    #pragma unroll 2
    for (int k0 = 0; k0 < K; k0 += 32) {
        // ---- store prefetched tile to LDS ----
        if (A_BF16) {
            *(short8*)&As[sr][kg] = pa_bf;
        } else {
            uint4 pk;
            pk.x = (unsigned int)f2bf(pa0.x) | ((unsigned int)f2bf(pa0.y) << 16);
            pk.y = (unsigned int)f2bf(pa0.z) | ((unsigned int)f2bf(pa0.w) << 16);
            pk.z = (unsigned int)f2bf(pa1.x) | ((unsigned int)f2bf(pa1.y) << 16);
            pk.w = (unsigned int)f2bf(pa1.z) | ((unsigned int)f2bf(pa1.w) << 16);
            *(uint4*)&As[sr][kg] = pk;
        }
        #pragma unroll
        for (int i = 0; i < NTW; ++i) {
            const int slot = tid + i * 256;
            const int n  = slot >> 2;
            const int kk = (slot & 3) * 8;
            *(short8*)&Bs[n][kk] = pb[i];
        }
        __syncthreads();

        if (k0 + 32 < K) gload(k0 + 32);   // issue next tile's loads now

        short8 af[4];
        #pragma unroll
        for (int rg = 0; rg < 4; ++rg)
            af[rg] = *(const short8*)&As[rg * 16 + lm][lq * 8];
        #pragma unroll
        for (int nt = 0; nt < NTW; ++nt) {
            const short8 bf = *(const short8*)&Bs[(w * NTW + nt) * 16 + lm][lq * 8];
            #pragma unroll
            for (int rg = 0; rg < 4; ++rg)
                acc[rg][nt] = __builtin_amdgcn_mfma_f32_16x16x32_bf16(af[rg], bf, acc[rg][nt], 0, 0, 0);
        }
        __syncthreads();
    }

    // ---- epilogue ----
    #pragma unroll
    for (int nt = 0; nt < NTW; ++nt) {
        const int col = n0 + (w * NTW + nt) * 16 + lm;
        const float b = (col < nsplit) ? bias0[col] : bias1[col - nsplit];
        #pragma unroll
        for (int rg = 0; rg < 4; ++rg)
            #pragma unroll
            for (int r = 0; r < 4; ++r) {
                const int row = m0 + rg * 16 + lq * 4 + r;
                const float v = acc[rg][nt][r] + b;
                if (OUT_BF16) ((unsigned short*)Cv)[(size_t)row * N + col] = f2bf(v);
                else          ((float*)Cv)[(size_t)row * N + col] = v;
            }
    }
}

// ---------------- loc + softmax (in place over OA [row][384]) ----------------
// 256 threads = 2 rows x 128. t = h*16 + l*4 + p.
__global__ __launch_bounds__(256) void loc_aw_kernel(
    float* __restrict__ OA, const float* __restrict__ refp)
{
    const int tid = threadIdx.x;
    const int row = blockIdx.x * 2 + (tid >> 7);
    const int t = tid & 127;
    const int l = (t >> 2) & 3;
    float* rowp = OA + (size_t)row * 384;

    float logit = rowp[256 + t];
    float m = logit;
    #pragma unroll
    for (int d = 8; d >= 1; d >>= 1) m = fmaxf(m, __shfl_xor(m, d, 16));
    float e = __expf(logit - m);
    float s = e;
    #pragma unroll
    for (int d = 8; d >= 1; d >>= 1) s += __shfl_xor(s, d, 16);
    rowp[256 + t] = e / s;

    const float ox = rowp[t * 2 + 0];
    const float oy = rowp[t * 2 + 1];
    const float rx = refp[(size_t)row * 8 + l * 2 + 0];
    const float ry = refp[(size_t)row * 8 + l * 2 + 1];
    const float Wl = (float)LVL_W[l];
    const float Hl = (float)LVL_H[l];
    const float lx = rx + ox / Wl;      // mimic reference op order
    const float ly = ry + oy / Hl;
    rowp[t * 2 + 0] = lx * Wl - 0.5f;
    rowp[t * 2 + 1] = ly * Hl - 0.5f;
}

// ---------------- bilinear sampling, level-split + pipelined loads ----------------
// Block = 256 threads = 2 rows x 2 level-groups x 64 lanes.
// wave w: r2 = w>>1 (row within block), lg = w&1 (levels 2*lg, 2*lg+1).
// lane l: h = l>>3, channels (l&7)*4 .. +4 (ushort4, 8 lanes x 8B = 64B per head-corner).
// OA row staged in LDS; corner loads double-buffered 2 samples (8 loads) deep.
// lg=1 partials reduced into lg=0 via LDS.
__global__ __launch_bounds__(256) void sample_kernel(
    const unsigned short* __restrict__ V,   // bf16 [b, pix, 256]
    const float* __restrict__ OA,           // [row][384]: coords then weights
    unsigned short* __restrict__ ACC)       // bf16 [row][256]
{
    __shared__ float oas[2][384];
    __shared__ float red[2][64][4];

    const int tid = threadIdx.x;
    const int w   = tid >> 6;
    const int r2  = w >> 1;
    const int lg  = w & 1;
    const int l64 = tid & 63;
    const int h   = l64 >> 3;
    const int c4  = (l64 & 7) * 4;
    const int row = blockIdx.x * 2 + r2;
    const int b   = row / LQ;

    // stage the two OA rows (768 floats) via float4
    if (tid < 192) {
        const int r = tid / 96;
        const int c = (tid % 96) * 4;
        *(float4*)&oas[r][c] =
            *(const float4*)&OA[(size_t)(blockIdx.x * 2 + r) * 384 + c];
    }
    __syncthreads();

    const unsigned short* vb = V + ((size_t)b * LQ * EMBED + h * HD + c4);

    float acc[4] = {0.f, 0.f, 0.f, 0.f};
    ushort4 dat[2][8];
    float   cw[2][8];

    auto prep = [&](int pp, int buf) {
        const int l = 2 * lg + (pp >> 1);           // wave-uniform
        const int Wl = LVL_W[l], Hl = LVL_H[l], st = LVL_ST[l];
        #pragma unroll
        for (int j = 0; j < 2; ++j) {
            const int p  = (pp & 1) * 2 + j;
            const int lp = l * 4 + p;
            const float gx  = oas[r2][h * 32 + lp * 2 + 0];
            const float gy  = oas[r2][h * 32 + lp * 2 + 1];
            const float wgt = oas[r2][256 + h * 16 + lp];

            const float fx = floorf(gx), fy = floorf(gy);
            const float wx = gx - fx,    wy = gy - fy;
            const int x0 = (int)fx, y0 = (int)fy;
            const int x1 = x0 + 1,  y1 = y0 + 1;

            const bool bx0 = ((unsigned)x0 < (unsigned)Wl);
            const bool bx1 = ((unsigned)x1 < (unsigned)Wl);
            const bool by0 = ((unsigned)y0 < (unsigned)Hl);
            const bool by1 = ((unsigned)y1 < (unsigned)Hl);
            cw[buf][j * 4 + 0] = (bx0 && by0) ? (1.f - wx) * (1.f - wy) * wgt : 0.f;
            cw[buf][j * 4 + 1] = (bx1 && by0) ? wx * (1.f - wy) * wgt : 0.f;
            cw[buf][j * 4 + 2] = (bx0 && by1) ? (1.f - wx) * wy * wgt : 0.f;
            cw[buf][j * 4 + 3] = (bx1 && by1) ? wx * wy * wgt : 0.f;

            const int cx0 = min(max(x0, 0), Wl - 1);
            const int cx1 = min(max(x1, 0), Wl - 1);
            const int cy0 = min(max(y0, 0), Hl - 1);
            const int cy1 = min(max(y1, 0), Hl - 1);
            dat[buf][j * 4 + 0] = *(const ushort4*)(vb + (size_t)(st + cy0 * Wl + cx0) * EMBED);
            dat[buf][j * 4 + 1] = *(const ushort4*)(vb + (size_t)(st + cy0 * Wl + cx1) * EMBED);
            dat[buf][j * 4 + 2] = *(const ushort4*)(vb + (size_t)(st + cy1 * Wl + cx0) * EMBED);
            dat[buf][j * 4 + 3] = *(const ushort4*)(vb + (size_t)(st + cy1 * Wl + cx1) * EMBED);
        }
    };
    auto consume = [&](int buf) {
        #pragma unroll
        for (int k = 0; k < 8; ++k) {
            const float wk = cw[buf][k];
            acc[0] = fmaf(wk, bf2f(dat[buf][k].x), acc[0]);
            acc[1] = fmaf(wk, bf2f(dat[buf][k].y), acc[1]);
            acc[2] = fmaf(wk, bf2f(dat[buf][k].z), acc[2]);
            acc[3] = fmaf(wk, bf2f(dat[buf][k].w), acc[3]);
        }
    };

    prep(0, 0);
    #pragma unroll
    for (int pp = 0; pp < 4; ++pp) {
        if (pp < 3) prep(pp + 1, (pp + 1) & 1);
        consume(pp & 1);
    }

    // ---- reduce lg=1 into lg=0, write out ----
    if (lg == 1) {
        red[r2][l64][0] = acc[0]; red[r2][l64][1] = acc[1];
        red[r2][l64][2] = acc[2]; red[r2][l64][3] = acc[3];
    }
    __syncthreads();
    if (lg == 0) {
        ushort4 o;
        o.x = f2bf(acc[0] + red[r2][l64][0]);
        o.y = f2bf(acc[1] + red[r2][l64][1]);
        o.z = f2bf(acc[2] + red[r2][l64][2]);
        o.w = f2bf(acc[3] + red[r2][l64][3]);
        *(ushort4*)(ACC + (size_t)row * EMBED + h * HD + c4) = o;
    }
}

// ---------------- launch ----------------
extern "C" void kernel_launch(void* const* d_in, const int* in_sizes, int n_in,
                              void* d_out, int out_size, void* d_ws, size_t ws_size,
                              hipStream_t stream) {
    const float* query  = (const float*)d_in[0];
    const float* refp   = (const float*)d_in[1];
    const float* value  = (const float*)d_in[2];
    // d_in[3] = value_spatial_shapes (static, hard-coded)
    const float* W_off  = (const float*)d_in[4];
    const float* b_off  = (const float*)d_in[5];
    const float* W_attn = (const float*)d_in[6];
    const float* b_attn = (const float*)d_in[7];
    const float* W_val  = (const float*)d_in[8];
    const float* b_val  = (const float*)d_in[9];
    const float* W_out  = (const float*)d_in[10];
    const float* b_out  = (const float*)d_in[11];
    float* out = (float*)d_out;

    // ---- workspace layout ----
    unsigned short* WT_oa  = (unsigned short*)d_ws;          // [384][256] bf16
    unsigned short* WT_val = WT_oa  + 384 * 256;             // [256][256] bf16
    unsigned short* WT_out = WT_val + 256 * 256;             // [256][256] bf16
    unsigned short* V      = WT_out + 256 * 256;             // [NROW][256] bf16
    float*          OA     = (float*)(V + (size_t)NROW * EMBED);        // [NROW][384] f32
    unsigned short* ACCb   = (unsigned short*)(OA + (size_t)NROW * 384); // [NROW][256] bf16

    dim3 blk(256);

    // 0. weight transpose + convert
    prep_weights<<<896, blk, 0, stream>>>(W_off, W_attn, W_val, W_out,
                                          WT_oa, WT_val, WT_out);
    // 1. V = bf16(value @ W_val + b_val)
    gemm_mfma<4, false, true><<<dim3(1, NROW / 64), blk, 0, stream>>>(
        value, WT_val, b_val, b_val, 256, V, 256);
    // 2. OA = query @ [W_off | W_attn] + bias  (N=384, two 192-col blocks)
    gemm_mfma<3, false, false><<<dim3(2, NROW / 64), blk, 0, stream>>>(
        query, WT_oa, b_off, b_attn, 256, OA, 384);
    // 3. softmax + pixel coords (in place over OA)
    loc_aw_kernel<<<NROW / 2, blk, 0, stream>>>(OA, refp);
    // 4. deformable sampling -> bf16 ACC
    sample_kernel<<<NROW / 2, blk, 0, stream>>>(V, OA, ACCb);
    // 5. out = ACC @ W_out + b_out
    gemm_mfma<4, true, false><<<dim3(1, NROW / 64), blk, 0, stream>>>(
        ACCb, WT_out, b_out, b_out, 256, out, 256);
}